// Round 9
// baseline (799.514 us; speedup 1.0000x reference)
//
#include <hip/hip_runtime.h>
#include <hip/hip_bf16.h>
#include <stdint.h>

#define M_DIM 8192
#define N_DIM 11008
#define K_DIM 4096
#define NQB 44032  // quant blocks: N*K/4/256
#define NCB 16384  // cast blocks:  M*K/8/256

typedef __attribute__((ext_vector_type(8))) short bf16x8;
typedef __attribute__((ext_vector_type(4))) float f32x4;

// ---------------- FP4 code table (bitsandbytes), fp32-exact ----------------
__device__ const float kCodes[16] = {
    -1.0f, -(float)(2.0 / 3.0), -0.5f, -(float)(1.0 / 3.0), -0.25f,
    -(float)(1.0 / 6.0), -0.0052083333f, -0.0f,
    0.0f, 0.0052083333f, (float)(1.0 / 6.0), 0.25f,
    (float)(1.0 / 3.0), 0.5f, (float)(2.0 / 3.0), 1.0f};

__device__ __forceinline__ float fp4_bound(int i) {
  return (kCodes[i] + kCodes[i + 1]) * 0.5f;
}

__device__ __forceinline__ unsigned short f2bf(float f) {
  uint32_t u = __float_as_uint(f);
  u = (u + 0x7FFFu + ((u >> 16) & 1u)) >> 16;
  return (unsigned short)u;
}

__device__ __forceinline__ float fp4_rt(float w, float d, float am) {
  float n = w / d;
  int idx = 0;
#pragma unroll
  for (int i = 0; i < 15; ++i) idx += (n > fp4_bound(i)) ? 1 : 0;
  return kCodes[idx] * am;
}

__device__ __forceinline__ uint32_t pack2(float lo, float hi) {
  return (uint32_t)f2bf(lo) | ((uint32_t)f2bf(hi) << 16);
}

// ---------------- Kernel 1: fused {W quant->dequant->bf16} + {x cast} -------
__global__ void prep_kernel(const float* __restrict__ W,
                            unsigned short* __restrict__ Wq,
                            const float* __restrict__ X,
                            uint32_t* __restrict__ Y) {
  const int bid = blockIdx.x;
  if (bid < NQB) {
    int t = bid * 256 + threadIdx.x;
    size_t base = (size_t)t * 4;
    float4 v = *reinterpret_cast<const float4*>(W + base);
    float am =
        fmaxf(fmaxf(fabsf(v.x), fabsf(v.y)), fmaxf(fabsf(v.z), fabsf(v.w)));
    am = fmaxf(am, __shfl_xor(am, 1));
    am = fmaxf(am, __shfl_xor(am, 2));
    am = fmaxf(am, __shfl_xor(am, 4));
    am = fmaxf(am, __shfl_xor(am, 8));
    float d = fmaxf(am, 1e-12f);
    ushort4 o;
    o.x = f2bf(fp4_rt(v.x, d, am));
    o.y = f2bf(fp4_rt(v.y, d, am));
    o.z = f2bf(fp4_rt(v.z, d, am));
    o.w = f2bf(fp4_rt(v.w, d, am));
    *reinterpret_cast<ushort4*>(Wq + base) = o;
  } else {
    int t = (bid - NQB) * 256 + threadIdx.x;
    size_t base = (size_t)t * 8;
    float4 a = *reinterpret_cast<const float4*>(X + base);
    float4 b = *reinterpret_cast<const float4*>(X + base + 4);
    uint4 o;
    o.x = pack2(a.x, a.y);
    o.y = pack2(a.z, a.w);
    o.z = pack2(b.x, b.y);
    o.w = pack2(b.z, b.w);
    *reinterpret_cast<uint4*>(Y + (size_t)t * 4) = o;
  }
}

// ---------------- Kernel 2: 256x256 m201-faithful 8-phase bf16 GEMM ---------
// C[M,N] = A[M,K]*B[N,K]^T + bias.  BM=BN=256, BK=64, 512 thr = 8 waves
// (2M x 4N), acc[8][4] f32x4/wave, 16x16x32 MFMA, 16 MFMA/phase.
// LDS 128KB = [2 buf][A.kk0, A.kk1, B.kk0, B.kk1][16KB half]; half = 256 rows
// x 32 k-elems (64B rows).  K-SPLIT halves free progressively -> half-granular
// staging ring: each phase stages the half freed last phase; each staged half
// has 5-7 phases of HBM cover; vmcnt(6) at ph3/ph7 only (NEVER 0 in loop).
// Phase: {4-8 ds_read; 1 half stage; BAR; lgkm(0); setprio1; 16 MFMA;
// setprio0; [vmcnt(6)]; BAR}.  Swizzle (R7 hw-proven, 0 conflicts):
// phys = row*64 + (kbyte ^ (((row>>1)&3)<<4)); staging keeps LDS dest linear,
// inverse-swizzles the global source (rule #21).
#define GLOAD(src, dst)                                                        \
  __builtin_amdgcn_global_load_lds(                                           \
      (const __attribute__((address_space(1))) void*)(src),                   \
      (__attribute__((address_space(3))) void*)(dst), 16, 0, 0)

#define BAR_LGKM0()                                                            \
  __builtin_amdgcn_s_barrier();                                                \
  asm volatile("s_waitcnt lgkmcnt(0)" ::: "memory");                           \
  __builtin_amdgcn_sched_barrier(0);                                           \
  __builtin_amdgcn_s_setprio(1);

#define END_PH()                                                               \
  __builtin_amdgcn_s_setprio(0);                                               \
  __builtin_amdgcn_sched_barrier(0);                                           \
  __builtin_amdgcn_s_barrier();

#define END_PH_VM6()                                                           \
  __builtin_amdgcn_s_setprio(0);                                               \
  __builtin_amdgcn_sched_barrier(0);                                           \
  asm volatile("s_waitcnt vmcnt(6)" ::: "memory");                             \
  __builtin_amdgcn_s_barrier();

// stage one half: SHALF 0=A.kk0 1=A.kk1 2=B.kk0 3=B.kk1, tile TT
#define ST_(SBUF, SHALF, TT)                                                   \
  {                                                                            \
    const short* s_ =                                                          \
        (((SHALF) < 2) ? Asrc : Bsrc) + (TT) * 64 + ((SHALF)&1) * 32;          \
    GLOAD(s_, &lds[SBUF][SHALF][wu0]);                                         \
    GLOAD(s_ + (size_t)128 * K_DIM, &lds[SBUF][SHALF][wu1]);                   \
  }

// even phase: 8 reads (A m0-3 + B n0-3 of [BUF][KK]), MFMA acc[0-3]
#define PH_E(BUF, KK, SBUF, SHALF, TT)                                         \
  _Pragma("unroll") for (int m = 0; m < 4; ++m) af[m] =                        \
      *(const bf16x8*)((const char*)&lds[BUF][KK][0] + aOff + m * 1024);       \
  _Pragma("unroll") for (int n = 0; n < 4; ++n) bf[n] =                        \
      *(const bf16x8*)((const char*)&lds[BUF][2 + KK][0] + bOff + n * 1024);   \
  ST_(SBUF, SHALF, TT);                                                        \
  BAR_LGKM0();                                                                 \
  _Pragma("unroll") for (int m = 0; m < 4; ++m)                                \
      _Pragma("unroll") for (int n = 0; n < 4; ++n) acc[m][n] =                \
          __builtin_amdgcn_mfma_f32_16x16x32_bf16(af[m], bf[n], acc[m][n], 0,  \
                                                  0, 0);                       \
  END_PH();

// odd phase: 4 reads (A m4-7), B persists, MFMA acc[4-7]; VM = END macro
#define PH_O(BUF, KK, SBUF, SHALF, TT, ENDM)                                   \
  _Pragma("unroll") for (int m = 0; m < 4; ++m) af[m] =                        \
      *(const bf16x8*)((const char*)&lds[BUF][KK][0] + aOff + (4 + m) * 1024); \
  ST_(SBUF, SHALF, TT);                                                        \
  BAR_LGKM0();                                                                 \
  _Pragma("unroll") for (int m = 0; m < 4; ++m)                                \
      _Pragma("unroll") for (int n = 0; n < 4; ++n) acc[4 + m][n] =            \
          __builtin_amdgcn_mfma_f32_16x16x32_bf16(af[m], bf[n], acc[4 + m][n], \
                                                  0, 0, 0);                    \
  ENDM();

__global__ __launch_bounds__(512, 2) void gemm256_kernel(
    const short* __restrict__ A, const short* __restrict__ B,
    const float* __restrict__ bias, float* __restrict__ C) {
  __shared__ short lds[2][4][8192];  // [buf][A0,A1,B0,B1][256 rows x 64B]

  const int tid = threadIdx.x;
  const int wave = tid >> 6;
  const int lane = tid & 63;
  const int l15 = lane & 15;
  const int q4 = lane >> 4;
  const int wm = wave >> 2;  // 0..1
  const int wn = wave & 3;   // 0..3

  // XCD-chunked swizzle: 1280 blocks = 8 XCDs x 160 (4 M-rows x 40 N-cols)
  const int bid = blockIdx.x;
  const int g = bid & 7;
  const int idx = bid >> 3;  // 0..159
  const int brow = (g * 4 + (idx & 3)) * 256;
  const int bcol = (idx >> 2) * 256;  // tile-cols 0..39

  // staging source (inverse-swizzled global addr; linear LDS dest)
  // thread t: phys row = t>>2 (0..127; +128 via 2nd gload), phys slot = t&3
  //   -> logical slot = (t&3) ^ ((t>>3)&3)    [(row>>1)&3 = (t>>3)&3]
  const int srow = tid >> 2;
  const int scol = ((tid & 3) ^ ((tid >> 3) & 3)) << 3;
  const short* Asrc = A + (size_t)(brow + srow) * K_DIM + scol;
  const short* Bsrc = B + (size_t)(bcol + srow) * K_DIM + scol;
  const int wu0 = wave * 512;         // shorts; wave-uniform (lane*16B by HW)
  const int wu1 = wave * 512 + 4096;  // rows 128-255 chunk

  // fragment read offsets: row (A) = wm*128+m*16+l15, (B) = wn*64+n*16+l15;
  // (row>>1)&3 == (l15>>1)&3 (16-multiples drop out). 16B slot = q4.
  const int okA = (q4 ^ ((l15 >> 1) & 3)) << 4;
  const int aOff = (wm * 128 + l15) * 64 + okA;
  const int bOff = (wn * 64 + l15) * 64 + okA;

  f32x4 acc[8][4] = {};
  bf16x8 af[4], bf[4];

  // ---- prologue: tile0 all 4 halves -> buf0; tile1 B0,A0,B1 -> buf1 ----
  ST_(0, 2, 0);  // b0.B.kk0
  ST_(0, 0, 0);  // b0.A.kk0
  ST_(0, 3, 0);  // b0.B.kk1
  ST_(0, 1, 0);  // b0.A.kk1
  ST_(1, 2, 1);  // b1.B.kk0
  ST_(1, 0, 1);  // b1.A.kk0
  ST_(1, 3, 1);  // b1.B.kk1
  asm volatile("s_waitcnt vmcnt(6)" ::: "memory");  // tile0's 8 loads landed
  __builtin_amdgcn_s_barrier();

  for (int i = 0; i < 32; ++i) {
    const int t1 = 2 * i + 1;                          // <= 63
    const int t2 = (2 * i + 2 < 64) ? 2 * i + 2 : 63;  // clamped tail (dead)
    const int t3 = (2 * i + 3 < 64) ? 2 * i + 3 : 63;

    // stage slot = (last read phase of that half) + 1; vmcnt(6) at ph3/ph7
    PH_E(0, 0, /*stage*/ 1, 1, t1);          // ph0: read b0.kk0; st b1.A1<-t1
    PH_O(0, 0, 0, 2, t2, END_PH);            // ph1: st b0.B0<-t2
    PH_E(0, 1, 0, 0, t2);                    // ph2: st b0.A0<-t2
    PH_O(0, 1, 0, 3, t2, END_PH_VM6);        // ph3: st b0.B1<-t2; vmcnt(6)
    PH_E(1, 0, 0, 1, t2);                    // ph4: st b0.A1<-t2
    PH_O(1, 0, 1, 2, t3, END_PH);            // ph5: st b1.B0<-t3
    PH_E(1, 1, 1, 0, t3);                    // ph6: st b1.A0<-t3
    PH_O(1, 1, 1, 3, t3, END_PH_VM6);        // ph7: st b1.B1<-t3; vmcnt(6)
  }

  // ---- epilogue: C/D layout col=lane&15, row=(lane>>4)*4+j ----
  const int crow0 = brow + wm * 128 + q4 * 4;
  const int ccol0 = bcol + wn * 64 + l15;
#pragma unroll
  for (int n = 0; n < 4; ++n) {
    const float bv = bias[ccol0 + n * 16];
#pragma unroll
    for (int m = 0; m < 8; ++m) {
      const size_t rb = (size_t)(crow0 + m * 16) * N_DIM + (ccol0 + n * 16);
#pragma unroll
      for (int j = 0; j < 4; ++j) C[rb + (size_t)j * N_DIM] = acc[m][n][j] + bv;
    }
  }
}

// ---------------- Kernel 3: 128x128 m97 tail GEMM (N-cols 10240..11007) -----
__global__ __launch_bounds__(256, 2) void gemm_bt_kernel(
    const short* __restrict__ A, const short* __restrict__ B,
    const float* __restrict__ bias, float* __restrict__ C) {
  __shared__ short Alds[128 * 32];
  __shared__ short Blds[128 * 32];

  const int tid = threadIdx.x;
  const int wave = tid >> 6;
  const int lane = tid & 63;
  const int wr = wave >> 1;
  const int wc = wave & 1;

  const int bid = blockIdx.x;  // 0..383
  const int brow = (bid & 63) * 128;
  const int bcol = (80 + (bid >> 6)) * 128;  // cols 10240..11007

  const int tr = tid >> 2;
  const int tc = (tid & 3) * 8;
  const short* Ag = A + (size_t)(brow + tr) * K_DIM + tc;
  const short* Bg = B + (size_t)(bcol + tr) * K_DIM + tc;

  short* AldsW = &Alds[wave * 512];
  short* BldsW = &Blds[wave * 512];

  f32x4 acc[4][4] = {};

  const int la = (lane & 15) * 32 + (lane >> 4) * 8;
  const short* Ar = &Alds[(wr * 64) * 32 + la];
  const short* Br = &Blds[(wc * 64) * 32 + la];

  for (int k0 = 0; k0 < K_DIM; k0 += 32) {
    GLOAD(Ag, AldsW);
    GLOAD(Ag + (size_t)64 * K_DIM, AldsW + 2048);
    GLOAD(Bg, BldsW);
    GLOAD(Bg + (size_t)64 * K_DIM, BldsW + 2048);
    __syncthreads();

    bf16x8 af[4], bfr[4];
#pragma unroll
    for (int m = 0; m < 4; ++m)
      af[m] = *reinterpret_cast<const bf16x8*>(Ar + m * 16 * 32);
#pragma unroll
    for (int n = 0; n < 4; ++n)
      bfr[n] = *reinterpret_cast<const bf16x8*>(Br + n * 16 * 32);

#pragma unroll
    for (int m = 0; m < 4; ++m)
#pragma unroll
      for (int n = 0; n < 4; ++n)
        acc[m][n] = __builtin_amdgcn_mfma_f32_16x16x32_bf16(af[m], bfr[n],
                                                            acc[m][n], 0, 0, 0);

    __syncthreads();
    Ag += 32;
    Bg += 32;
  }

  const int crow0 = brow + wr * 64 + (lane >> 4) * 4;
  const int ccol0 = bcol + wc * 64 + (lane & 15);
#pragma unroll
  for (int n = 0; n < 4; ++n) {
    const int cc = ccol0 + n * 16;
    const float bv = bias[cc];
#pragma unroll
    for (int m = 0; m < 4; ++m) {
      const size_t rbase = (size_t)(crow0 + m * 16) * N_DIM + cc;
#pragma unroll
      for (int j = 0; j < 4; ++j) C[rbase + (size_t)j * N_DIM] = acc[m][n][j] + bv;
    }
  }
}

extern "C" void kernel_launch(void* const* d_in, const int* in_sizes, int n_in,
                              void* d_out, int out_size, void* d_ws, size_t ws_size,
                              hipStream_t stream) {
  const float* x = (const float*)d_in[0];     // [8192, 4096]
  const float* w = (const float*)d_in[1];     // [11008, 4096]
  const float* bias = (const float*)d_in[2];  // [11008]
  float* out = (float*)d_out;                 // [8192, 11008]

  unsigned short* wq = (unsigned short*)d_ws;       // N*K bf16
  unsigned short* xb = wq + (size_t)N_DIM * K_DIM;  // M*K bf16

  prep_kernel<<<NQB + NCB, 256, 0, stream>>>(w, wq, x, (uint32_t*)xb);
  // main: tile-cols 0..39 (1280 blocks = 5 clean rounds, zero tail)
  gemm256_kernel<<<dim3(1280), 512, 0, stream>>>((const short*)xb,
                                                 (const short*)wq, bias, out);
  // tail: tile-cols 40..42 as 384 blocks of 128x128 (multi-resident)
  gemm_bt_kernel<<<dim3(384), 256, 0, stream>>>((const short*)xb,
                                                (const short*)wq, bias, out);
}

// Round 10
// 764.171 us; speedup vs baseline: 1.0463x; 1.0463x over previous
//
#include <hip/hip_runtime.h>
#include <hip/hip_bf16.h>
#include <stdint.h>

#define M_DIM 8192
#define N_DIM 11008
#define K_DIM 4096
#define NQB 44032  // quant blocks: N*K/4/256
#define NCB 16384  // cast blocks:  M*K/8/256
#define NMAIN 1280 // main 256x256 blocks (5 clean rounds)

typedef __attribute__((ext_vector_type(8))) short bf16x8;
typedef __attribute__((ext_vector_type(4))) float f32x4;

// ---------------- FP4 code table (bitsandbytes), fp32-exact ----------------
__device__ const float kCodes[16] = {
    -1.0f, -(float)(2.0 / 3.0), -0.5f, -(float)(1.0 / 3.0), -0.25f,
    -(float)(1.0 / 6.0), -0.0052083333f, -0.0f,
    0.0f, 0.0052083333f, (float)(1.0 / 6.0), 0.25f,
    (float)(1.0 / 3.0), 0.5f, (float)(2.0 / 3.0), 1.0f};

__device__ __forceinline__ float fp4_bound(int i) {
  return (kCodes[i] + kCodes[i + 1]) * 0.5f;
}

__device__ __forceinline__ unsigned short f2bf(float f) {
  uint32_t u = __float_as_uint(f);
  u = (u + 0x7FFFu + ((u >> 16) & 1u)) >> 16;
  return (unsigned short)u;
}

__device__ __forceinline__ float fp4_rt(float w, float d, float am) {
  float n = w / d;
  int idx = 0;
#pragma unroll
  for (int i = 0; i < 15; ++i) idx += (n > fp4_bound(i)) ? 1 : 0;
  return kCodes[idx] * am;
}

__device__ __forceinline__ uint32_t pack2(float lo, float hi) {
  return (uint32_t)f2bf(lo) | ((uint32_t)f2bf(hi) << 16);
}

// ---------------- Kernel 1: fused {W quant->dequant->bf16} + {x cast} -------
__global__ void prep_kernel(const float* __restrict__ W,
                            unsigned short* __restrict__ Wq,
                            const float* __restrict__ X,
                            uint32_t* __restrict__ Y) {
  const int bid = blockIdx.x;
  if (bid < NQB) {
    int t = bid * 256 + threadIdx.x;
    size_t base = (size_t)t * 4;
    float4 v = *reinterpret_cast<const float4*>(W + base);
    float am =
        fmaxf(fmaxf(fabsf(v.x), fabsf(v.y)), fmaxf(fabsf(v.z), fabsf(v.w)));
    am = fmaxf(am, __shfl_xor(am, 1));
    am = fmaxf(am, __shfl_xor(am, 2));
    am = fmaxf(am, __shfl_xor(am, 4));
    am = fmaxf(am, __shfl_xor(am, 8));
    float d = fmaxf(am, 1e-12f);
    ushort4 o;
    o.x = f2bf(fp4_rt(v.x, d, am));
    o.y = f2bf(fp4_rt(v.y, d, am));
    o.z = f2bf(fp4_rt(v.z, d, am));
    o.w = f2bf(fp4_rt(v.w, d, am));
    *reinterpret_cast<ushort4*>(Wq + base) = o;
  } else {
    int t = (bid - NQB) * 256 + threadIdx.x;
    size_t base = (size_t)t * 8;
    float4 a = *reinterpret_cast<const float4*>(X + base);
    float4 b = *reinterpret_cast<const float4*>(X + base + 4);
    uint4 o;
    o.x = pack2(a.x, a.y);
    o.y = pack2(a.z, a.w);
    o.z = pack2(b.x, b.y);
    o.w = pack2(b.z, b.w);
    *reinterpret_cast<uint4*>(Y + (size_t)t * 4) = o;
  }
}

// ---------------- Kernel 2: combined GEMM ------------------------------------
// bid < 1280: R8-proven 256x256 8-phase pipelined body (583us/1280 tiles,
//   MfmaUtil 57.7, 0 bank conflicts). Covers N-cols 0..10239, 5 clean rounds.
// bid >= 1280: 192 tail blocks; each runs TWO independent 128x128 m97 tiles
//   (waves 0-3 / 4-7, disjoint 16KB LDS carve-outs; identical loop counts so
//   block-wide barriers align). Covers N-cols 10240..11007. Dispatched last ->
//   backfills CUs as round-5 main blocks drain (~40us vs 116us full round).
#define GLOAD(src, dst)                                                        \
  __builtin_amdgcn_global_load_lds(                                           \
      (const __attribute__((address_space(1))) void*)(src),                   \
      (__attribute__((address_space(3))) void*)(dst), 16, 0, 0)

#define WAIT_LGKM(N)                                                           \
  asm volatile("s_waitcnt lgkmcnt(" #N ")" ::: "memory");                      \
  __builtin_amdgcn_sched_barrier(0);                                           \
  __builtin_amdgcn_s_setprio(1);

#define ENDBAR()                                                               \
  __builtin_amdgcn_s_setprio(0);                                               \
  __builtin_amdgcn_sched_barrier(0);                                           \
  __builtin_amdgcn_s_barrier();

#define ENDBAR_VM0()                                                           \
  __builtin_amdgcn_s_setprio(0);                                               \
  __builtin_amdgcn_sched_barrier(0);                                           \
  asm volatile("s_waitcnt vmcnt(0)" ::: "memory");                             \
  __builtin_amdgcn_s_barrier();

__global__ __launch_bounds__(512, 2) void gemm_comb_kernel(
    const short* __restrict__ A, const short* __restrict__ B,
    const float* __restrict__ bias, float* __restrict__ C) {
  __shared__ short lds[2][4][8192];  // 128KB

  const int tid = threadIdx.x;
  const int lane = tid & 63;

  if (blockIdx.x < NMAIN) {
    // ================= MAIN: 256x256 8-phase pipelined (R8 verbatim) =======
    const int wave = tid >> 6;
    const int l15 = lane & 15;
    const int q4 = lane >> 4;
    const int wm = wave >> 2;  // 0..1
    const int wn = wave & 3;   // 0..3

    const int bid = blockIdx.x;
    const int g = bid & 7;
    const int idx = bid >> 3;  // 0..159
    const int brow = (g * 4 + (idx & 3)) * 256;
    const int bcol = (idx >> 2) * 256;  // tile-cols 0..39

    const int srow = tid >> 3;
    const int scol = ((tid & 7) ^ ((tid >> 3) & 7)) << 3;
    const short* Asrc = A + (size_t)(brow + srow) * K_DIM + scol;
    const short* Bsrc = B + (size_t)(bcol + srow) * K_DIM + scol;
    const int wu0 = wave * 512;
    const int wu1 = 4096 + wave * 512;

    auto stageA = [&](int buf, int half, int t) {
      const short* s = Asrc + (size_t)half * 128 * K_DIM + t * 64;
      GLOAD(s, &lds[buf][half][wu0]);
      GLOAD(s + (size_t)64 * K_DIM, &lds[buf][half][wu1]);
    };
    auto stageB = [&](int buf, int half, int t) {
      const short* s = Bsrc + (size_t)half * 128 * K_DIM + t * 64;
      GLOAD(s, &lds[buf][2 + half][wu0]);
      GLOAD(s + (size_t)64 * K_DIM, &lds[buf][2 + half][wu1]);
    };

    const int offk0 = ((q4 ^ (l15 & 7)) << 4);
    const int offk1 = offk0 ^ 64;
    const char* aP[2] = {(const char*)&lds[0][wm][0] + l15 * 128,
                         (const char*)&lds[1][wm][0] + l15 * 128};
    const char* bP[2] = {
        (const char*)&lds[0][2 + (wn >> 1)][0] + (wn & 1) * 8192 + l15 * 128,
        (const char*)&lds[1][2 + (wn >> 1)][0] + (wn & 1) * 8192 + l15 * 128};

    f32x4 acc[8][4] = {};
    bf16x8 afA[4], afB[4], bfA[4], bfB[4];

    stageB(0, 0, 0);
    stageB(0, 1, 0);
    stageA(0, 0, 0);
    stageA(0, 1, 0);
    stageB(1, 0, 1);
    asm volatile("s_waitcnt vmcnt(2)" ::: "memory");
    __builtin_amdgcn_s_barrier();
#pragma unroll
    for (int m = 0; m < 4; ++m)
      afA[m] = *(const bf16x8*)(aP[0] + m * 2048 + offk0);
#pragma unroll
    for (int n = 0; n < 4; ++n)
      bfA[n] = *(const bf16x8*)(bP[0] + n * 2048 + offk0);

    for (int i = 0; i < 32; ++i) {
      const int t1 = 2 * i + 1;
      const int t2 = (2 * i + 2 < 64) ? 2 * i + 2 : 63;
      const int t3 = (2 * i + 3 < 64) ? 2 * i + 3 : 63;

      // ph0
#pragma unroll
      for (int m = 0; m < 4; ++m)
        afB[m] = *(const bf16x8*)(aP[0] + (4 + m) * 2048 + offk0);
      stageB(1, 1, t1);
      WAIT_LGKM(4);
#pragma unroll
      for (int m = 0; m < 4; ++m)
#pragma unroll
        for (int n = 0; n < 4; ++n)
          acc[m][n] = __builtin_amdgcn_mfma_f32_16x16x32_bf16(
              afA[m], bfA[n], acc[m][n], 0, 0, 0);
      ENDBAR();

      // ph1
#pragma unroll
      for (int m = 0; m < 4; ++m)
        afA[m] = *(const bf16x8*)(aP[0] + m * 2048 + offk1);
#pragma unroll
      for (int n = 0; n < 4; ++n)
        bfB[n] = *(const bf16x8*)(bP[0] + n * 2048 + offk1);
      stageA(1, 0, t1);
      stageA(1, 1, t1);
      WAIT_LGKM(8);
#pragma unroll
      for (int m = 0; m < 4; ++m)
#pragma unroll
        for (int n = 0; n < 4; ++n)
          acc[4 + m][n] = __builtin_amdgcn_mfma_f32_16x16x32_bf16(
              afB[m], bfA[n], acc[4 + m][n], 0, 0, 0);
      ENDBAR();

      // ph2
#pragma unroll
      for (int m = 0; m < 4; ++m)
        afB[m] = *(const bf16x8*)(aP[0] + (4 + m) * 2048 + offk1);
      WAIT_LGKM(4);
#pragma unroll
      for (int m = 0; m < 4; ++m)
#pragma unroll
        for (int n = 0; n < 4; ++n)
          acc[m][n] = __builtin_amdgcn_mfma_f32_16x16x32_bf16(
              afA[m], bfB[n], acc[m][n], 0, 0, 0);
      ENDBAR_VM0();

      // ph3
#pragma unroll
      for (int m = 0; m < 4; ++m)
        afA[m] = *(const bf16x8*)(aP[1] + m * 2048 + offk0);
#pragma unroll
      for (int n = 0; n < 4; ++n)
        bfA[n] = *(const bf16x8*)(bP[1] + n * 2048 + offk0);
      stageB(0, 0, t2);
      WAIT_LGKM(8);
#pragma unroll
      for (int m = 0; m < 4; ++m)
#pragma unroll
        for (int n = 0; n < 4; ++n)
          acc[4 + m][n] = __builtin_amdgcn_mfma_f32_16x16x32_bf16(
              afB[m], bfB[n], acc[4 + m][n], 0, 0, 0);
      ENDBAR();

      // ph4
#pragma unroll
      for (int m = 0; m < 4; ++m)
        afB[m] = *(const bf16x8*)(aP[1] + (4 + m) * 2048 + offk0);
      stageB(0, 1, t2);
      WAIT_LGKM(4);
#pragma unroll
      for (int m = 0; m < 4; ++m)
#pragma unroll
        for (int n = 0; n < 4; ++n)
          acc[m][n] = __builtin_amdgcn_mfma_f32_16x16x32_bf16(
              afA[m], bfA[n], acc[m][n], 0, 0, 0);
      ENDBAR();

      // ph5
#pragma unroll
      for (int m = 0; m < 4; ++m)
        afA[m] = *(const bf16x8*)(aP[1] + m * 2048 + offk1);
#pragma unroll
      for (int n = 0; n < 4; ++n)
        bfB[n] = *(const bf16x8*)(bP[1] + n * 2048 + offk1);
      stageA(0, 0, t2);
      stageA(0, 1, t2);
      WAIT_LGKM(8);
#pragma unroll
      for (int m = 0; m < 4; ++m)
#pragma unroll
        for (int n = 0; n < 4; ++n)
          acc[4 + m][n] = __builtin_amdgcn_mfma_f32_16x16x32_bf16(
              afB[m], bfA[n], acc[4 + m][n], 0, 0, 0);
      ENDBAR();

      // ph6
#pragma unroll
      for (int m = 0; m < 4; ++m)
        afB[m] = *(const bf16x8*)(aP[1] + (4 + m) * 2048 + offk1);
      WAIT_LGKM(4);
#pragma unroll
      for (int m = 0; m < 4; ++m)
#pragma unroll
        for (int n = 0; n < 4; ++n)
          acc[m][n] = __builtin_amdgcn_mfma_f32_16x16x32_bf16(
              afA[m], bfB[n], acc[m][n], 0, 0, 0);
      ENDBAR_VM0();

      // ph7
#pragma unroll
      for (int m = 0; m < 4; ++m)
        afA[m] = *(const bf16x8*)(aP[0] + m * 2048 + offk0);
#pragma unroll
      for (int n = 0; n < 4; ++n)
        bfA[n] = *(const bf16x8*)(bP[0] + n * 2048 + offk0);
      stageB(1, 0, t3);
      WAIT_LGKM(8);
#pragma unroll
      for (int m = 0; m < 4; ++m)
#pragma unroll
        for (int n = 0; n < 4; ++n)
          acc[4 + m][n] = __builtin_amdgcn_mfma_f32_16x16x32_bf16(
              afB[m], bfB[n], acc[4 + m][n], 0, 0, 0);
      ENDBAR();
    }

    const int crow0 = brow + wm * 128 + q4 * 4;
    const int ccol0 = bcol + wn * 64 + l15;
#pragma unroll
    for (int n = 0; n < 4; ++n) {
      const float bv = bias[ccol0 + n * 16];
#pragma unroll
      for (int m = 0; m < 8; ++m) {
        const size_t rb = (size_t)(crow0 + m * 16) * N_DIM + (ccol0 + n * 16);
#pragma unroll
        for (int j = 0; j < 4; ++j)
          C[rb + (size_t)j * N_DIM] = acc[m][n][j] + bv;
      }
    }
  } else {
    // ================= TAIL: two independent 128x128 m97 tiles =============
    const int grp = tid >> 8;   // 0..1 (waves 0-3 / 4-7)
    const int tg = tid & 255;   // tid within group
    const int w4 = tg >> 6;     // wave within group 0..3
    const int wr = w4 >> 1;
    const int wc = w4 & 1;

    const int t = (blockIdx.x - NMAIN) * 2 + grp;  // tile 0..383
    const int brow = (t & 63) * 128;
    const int bcol = (80 + (t >> 6)) * 128;  // N-cols 10240..11007

    short* Alds = &lds[grp][0][0];  // 4096 shorts used of 8192
    short* Blds = &lds[grp][1][0];

    const int tr = tg >> 2;
    const int tc = (tg & 3) * 8;
    const short* Ag = A + (size_t)(brow + tr) * K_DIM + tc;
    const short* Bg = B + (size_t)(bcol + tr) * K_DIM + tc;

    short* AldsW = Alds + w4 * 512;
    short* BldsW = Blds + w4 * 512;

    f32x4 acc[4][4] = {};

    const int la = (lane & 15) * 32 + (lane >> 4) * 8;
    const short* Ar = Alds + (wr * 64) * 32 + la;
    const short* Br = Blds + (wc * 64) * 32 + la;

    for (int k0 = 0; k0 < K_DIM; k0 += 32) {
      GLOAD(Ag, AldsW);
      GLOAD(Ag + (size_t)64 * K_DIM, AldsW + 2048);
      GLOAD(Bg, BldsW);
      GLOAD(Bg + (size_t)64 * K_DIM, BldsW + 2048);
      __syncthreads();  // both groups: identical loop count -> aligned

      bf16x8 af[4], bfr[4];
#pragma unroll
      for (int m = 0; m < 4; ++m)
        af[m] = *reinterpret_cast<const bf16x8*>(Ar + m * 16 * 32);
#pragma unroll
      for (int n = 0; n < 4; ++n)
        bfr[n] = *reinterpret_cast<const bf16x8*>(Br + n * 16 * 32);

#pragma unroll
      for (int m = 0; m < 4; ++m)
#pragma unroll
        for (int n = 0; n < 4; ++n)
          acc[m][n] = __builtin_amdgcn_mfma_f32_16x16x32_bf16(
              af[m], bfr[n], acc[m][n], 0, 0, 0);

      __syncthreads();
      Ag += 32;
      Bg += 32;
    }

    const int crow0 = brow + wr * 64 + (lane >> 4) * 4;
    const int ccol0 = bcol + wc * 64 + (lane & 15);
#pragma unroll
    for (int n = 0; n < 4; ++n) {
      const int cc = ccol0 + n * 16;
      const float bv = bias[cc];
#pragma unroll
      for (int m = 0; m < 4; ++m) {
        const size_t rbase = (size_t)(crow0 + m * 16) * N_DIM + cc;
#pragma unroll
        for (int j = 0; j < 4; ++j)
          C[rbase + (size_t)j * N_DIM] = acc[m][n][j] + bv;
      }
    }
  }
}

extern "C" void kernel_launch(void* const* d_in, const int* in_sizes, int n_in,
                              void* d_out, int out_size, void* d_ws, size_t ws_size,
                              hipStream_t stream) {
  const float* x = (const float*)d_in[0];     // [8192, 4096]
  const float* w = (const float*)d_in[1];     // [11008, 4096]
  const float* bias = (const float*)d_in[2];  // [11008]
  float* out = (float*)d_out;                 // [8192, 11008]

  unsigned short* wq = (unsigned short*)d_ws;       // N*K bf16
  unsigned short* xb = wq + (size_t)N_DIM * K_DIM;  // M*K bf16

  prep_kernel<<<NQB + NCB, 256, 0, stream>>>(w, wq, x, (uint32_t*)xb);
  // 1280 main (256^2, 5 clean rounds) + 192 tail (2x 128^2 each, backfill)
  gemm_comb_kernel<<<dim3(NMAIN + 192), 512, 0, stream>>>(
      (const short*)xb, (const short*)wq, bias, out);
}

// Round 12
// 731.399 us; speedup vs baseline: 1.0931x; 1.0448x over previous
//
#include <hip/hip_runtime.h>
#include <hip/hip_bf16.h>
#include <stdint.h>

#define M_DIM 8192
#define N_DIM 11008
#define K_DIM 4096
#define NQB 44032  // quant blocks: N*K/4/256
#define NCB 16384  // cast blocks:  M*K/8/256

typedef __attribute__((ext_vector_type(8))) short bf16x8;
typedef __attribute__((ext_vector_type(4))) float f32x4;

// ---------------- FP4 code table (bitsandbytes), fp32-exact ----------------
__device__ const float kCodes[16] = {
    -1.0f, -(float)(2.0 / 3.0), -0.5f, -(float)(1.0 / 3.0), -0.25f,
    -(float)(1.0 / 6.0), -0.0052083333f, -0.0f,
    0.0f, 0.0052083333f, (float)(1.0 / 6.0), 0.25f,
    (float)(1.0 / 3.0), 0.5f, (float)(2.0 / 3.0), 1.0f};

__device__ __forceinline__ float fp4_bound(int i) {
  return (kCodes[i] + kCodes[i + 1]) * 0.5f;
}

__device__ __forceinline__ unsigned short f2bf(float f) {
  uint32_t u = __float_as_uint(f);
  u = (u + 0x7FFFu + ((u >> 16) & 1u)) >> 16;
  return (unsigned short)u;
}

__device__ __forceinline__ float fp4_rt(float w, float d, float am) {
  float n = w / d;
  int idx = 0;
#pragma unroll
  for (int i = 0; i < 15; ++i) idx += (n > fp4_bound(i)) ? 1 : 0;
  return kCodes[idx] * am;
}

__device__ __forceinline__ uint32_t pack2(float lo, float hi) {
  return (uint32_t)f2bf(lo) | ((uint32_t)f2bf(hi) << 16);
}

// ---------------- Kernel 1: fused {W quant->dequant->bf16} + {x cast} -------
// Nontemporal loads (ext-vector f32x4 -- HIP float4 class is rejected by the
// builtin): W and x are single-use streams; keep L3 free for Wq/xb.
__global__ void prep_kernel(const float* __restrict__ W,
                            unsigned short* __restrict__ Wq,
                            const float* __restrict__ X,
                            uint32_t* __restrict__ Y) {
  const int bid = blockIdx.x;
  if (bid < NQB) {
    int t = bid * 256 + threadIdx.x;
    size_t base = (size_t)t * 4;
    f32x4 v = __builtin_nontemporal_load(
        reinterpret_cast<const f32x4*>(W + base));
    float am =
        fmaxf(fmaxf(fabsf(v[0]), fabsf(v[1])), fmaxf(fabsf(v[2]), fabsf(v[3])));
    am = fmaxf(am, __shfl_xor(am, 1));
    am = fmaxf(am, __shfl_xor(am, 2));
    am = fmaxf(am, __shfl_xor(am, 4));
    am = fmaxf(am, __shfl_xor(am, 8));
    float d = fmaxf(am, 1e-12f);
    ushort4 o;
    o.x = f2bf(fp4_rt(v[0], d, am));
    o.y = f2bf(fp4_rt(v[1], d, am));
    o.z = f2bf(fp4_rt(v[2], d, am));
    o.w = f2bf(fp4_rt(v[3], d, am));
    *reinterpret_cast<ushort4*>(Wq + base) = o;
  } else {
    int t = (bid - NQB) * 256 + threadIdx.x;
    size_t base = (size_t)t * 8;
    f32x4 a = __builtin_nontemporal_load(
        reinterpret_cast<const f32x4*>(X + base));
    f32x4 b = __builtin_nontemporal_load(
        reinterpret_cast<const f32x4*>(X + base + 4));
    uint4 o;
    o.x = pack2(a[0], a[1]);
    o.y = pack2(a[2], a[3]);
    o.z = pack2(b[0], b[1]);
    o.w = pack2(b[2], b[3]);
    *reinterpret_cast<uint4*>(Y + (size_t)t * 4) = o;
  }
}

// ---------------- Kernel 2: 256x256 8-phase PIPELINED bf16 GEMM (R5 base) ---
// C[M,N] = A[M,K]*B[N,K]^T + bias.  BM=BN=256, BK=64, 512 thr = 8 waves
// (2M x 4N), acc[8][4], 16x16x32 MFMA.  LDS 128KB [2 buf][A0,A1,B0,B1][16KB].
// Register-pipelined reads (1 phase ahead, counted lgkm), 1 barrier/phase,
// vmcnt(0) only at buffer handoff (ph2/ph6).  Full 3-bit swizzle
// (phys = row*128 + (colbyte ^ ((row&7)<<4))): 0 bank conflicts (r4-proven).
// Grid 1376 (ragged 5.375 rounds) beat every tail-split variant (R8-R10).
// NEW vs R5: nontemporal C stores -- C's 360MB fp32 stream was evicting the
// L3-resident A/B panels (FETCH 550MB vs 157MB ideal).
#define GLOAD(src, dst)                                                        \
  __builtin_amdgcn_global_load_lds(                                           \
      (const __attribute__((address_space(1))) void*)(src),                   \
      (__attribute__((address_space(3))) void*)(dst), 16, 0, 0)

#define WAIT_LGKM(N)                                                           \
  asm volatile("s_waitcnt lgkmcnt(" #N ")" ::: "memory");                      \
  __builtin_amdgcn_sched_barrier(0);                                           \
  __builtin_amdgcn_s_setprio(1);

#define ENDBAR()                                                               \
  __builtin_amdgcn_s_setprio(0);                                               \
  __builtin_amdgcn_sched_barrier(0);                                           \
  __builtin_amdgcn_s_barrier();

#define ENDBAR_VM0()                                                           \
  __builtin_amdgcn_s_setprio(0);                                               \
  __builtin_amdgcn_sched_barrier(0);                                           \
  asm volatile("s_waitcnt vmcnt(0)" ::: "memory");                             \
  __builtin_amdgcn_s_barrier();

__global__ __launch_bounds__(512, 2) void gemm256_kernel(
    const short* __restrict__ A, const short* __restrict__ B,
    const float* __restrict__ bias, float* __restrict__ C) {
  __shared__ short lds[2][4][8192];  // [buf][A0,A1,B0,B1][16KB half]

  const int tid = threadIdx.x;
  const int wave = tid >> 6;
  const int lane = tid & 63;
  const int l15 = lane & 15;
  const int q4 = lane >> 4;
  const int wm = wave >> 2;  // 0..1
  const int wn = wave & 3;   // 0..3

  // XCD-chunked swizzle: 1376 blocks = 8 XCDs x 172
  const int bid = blockIdx.x;
  const int g = bid & 7;
  const int idx = bid >> 3;  // 0..171
  const int brow = (g * 4 + (idx & 3)) * 256;
  const int bcol = (idx >> 2) * 256;

  // staging source (inverse-swizzled global addr; linear LDS dest)
  const int srow = tid >> 3;                             // 0..63
  const int scol = ((tid & 7) ^ ((tid >> 3) & 7)) << 3;  // element col
  const short* Asrc = A + (size_t)(brow + srow) * K_DIM + scol;
  const short* Bsrc = B + (size_t)(bcol + srow) * K_DIM + scol;
  const int wu0 = wave * 512;
  const int wu1 = 4096 + wave * 512;

  auto stageA = [&](int buf, int half, int t) {
    const short* s = Asrc + (size_t)half * 128 * K_DIM + t * 64;
    GLOAD(s, &lds[buf][half][wu0]);
    GLOAD(s + (size_t)64 * K_DIM, &lds[buf][half][wu1]);
  };
  auto stageB = [&](int buf, int half, int t) {
    const short* s = Bsrc + (size_t)half * 128 * K_DIM + t * 64;
    GLOAD(s, &lds[buf][2 + half][wu0]);
    GLOAD(s + (size_t)64 * K_DIM, &lds[buf][2 + half][wu1]);
  };

  // fragment read bases (swizzled): frag(m,kk) phys byte =
  //   (m*16+l15)*128 + (((kk<<2|q4) ^ (l15&7)) << 4)
  const int offk0 = ((q4 ^ (l15 & 7)) << 4);
  const int offk1 = offk0 ^ 64;
  const char* aP[2] = {(const char*)&lds[0][wm][0] + l15 * 128,
                       (const char*)&lds[1][wm][0] + l15 * 128};
  const char* bP[2] = {
      (const char*)&lds[0][2 + (wn >> 1)][0] + (wn & 1) * 8192 + l15 * 128,
      (const char*)&lds[1][2 + (wn >> 1)][0] + (wn & 1) * 8192 + l15 * 128};

  f32x4 acc[8][4] = {};
  bf16x8 afA[4], afB[4], bfA[4], bfB[4];

  // ---- prologue: stage buf0 (tile0, 4 halves) + B(1,0, tile1) ----
  stageB(0, 0, 0);
  stageB(0, 1, 0);
  stageA(0, 0, 0);
  stageA(0, 1, 0);
  stageB(1, 0, 1);
  asm volatile("s_waitcnt vmcnt(2)" ::: "memory");  // buf0's 8 loads landed
  __builtin_amdgcn_s_barrier();
#pragma unroll
  for (int m = 0; m < 4; ++m) afA[m] = *(const bf16x8*)(aP[0] + m * 2048 + offk0);
#pragma unroll
  for (int n = 0; n < 4; ++n) bfA[n] = *(const bf16x8*)(bP[0] + n * 2048 + offk0);

  for (int i = 0; i < 32; ++i) {
    const int t1 = 2 * i + 1;
    const int t2 = (2 * i + 2 < 64) ? 2 * i + 2 : 63;  // clamped tail (dead)
    const int t3 = (2 * i + 3 < 64) ? 2 * i + 3 : 63;

    // ph0: read S1 (buf0.A m4-7 kk0); stage B(1,1,t1); MFMA Q0
#pragma unroll
    for (int m = 0; m < 4; ++m)
      afB[m] = *(const bf16x8*)(aP[0] + (4 + m) * 2048 + offk0);
    stageB(1, 1, t1);
    WAIT_LGKM(4);
#pragma unroll
    for (int m = 0; m < 4; ++m)
#pragma unroll
      for (int n = 0; n < 4; ++n)
        acc[m][n] = __builtin_amdgcn_mfma_f32_16x16x32_bf16(afA[m], bfA[n],
                                                            acc[m][n], 0, 0, 0);
    ENDBAR();

    // ph1: read S2 (buf0.A m0-3 kk1 + buf0.B kk1); stage A(1,*,t1); Q1
#pragma unroll
    for (int m = 0; m < 4; ++m)
      afA[m] = *(const bf16x8*)(aP[0] + m * 2048 + offk1);
#pragma unroll
    for (int n = 0; n < 4; ++n)
      bfB[n] = *(const bf16x8*)(bP[0] + n * 2048 + offk1);
    stageA(1, 0, t1);
    stageA(1, 1, t1);
    WAIT_LGKM(8);
#pragma unroll
    for (int m = 0; m < 4; ++m)
#pragma unroll
      for (int n = 0; n < 4; ++n)
        acc[4 + m][n] = __builtin_amdgcn_mfma_f32_16x16x32_bf16(
            afB[m], bfA[n], acc[4 + m][n], 0, 0, 0);
    ENDBAR();

    // ph2: read S3 (buf0.A m4-7 kk1); Q2; END: vmcnt(0) [buf1 landed]
#pragma unroll
    for (int m = 0; m < 4; ++m)
      afB[m] = *(const bf16x8*)(aP[0] + (4 + m) * 2048 + offk1);
    WAIT_LGKM(4);
#pragma unroll
    for (int m = 0; m < 4; ++m)
#pragma unroll
      for (int n = 0; n < 4; ++n)
        acc[m][n] = __builtin_amdgcn_mfma_f32_16x16x32_bf16(afA[m], bfB[n],
                                                            acc[m][n], 0, 0, 0);
    ENDBAR_VM0();

    // ph3: read S4 (buf1.A m0-3 kk0 + buf1.B kk0); stage B(0,0,t2); Q3
#pragma unroll
    for (int m = 0; m < 4; ++m)
      afA[m] = *(const bf16x8*)(aP[1] + m * 2048 + offk0);
#pragma unroll
    for (int n = 0; n < 4; ++n)
      bfA[n] = *(const bf16x8*)(bP[1] + n * 2048 + offk0);
    stageB(0, 0, t2);
    WAIT_LGKM(8);
#pragma unroll
    for (int m = 0; m < 4; ++m)
#pragma unroll
      for (int n = 0; n < 4; ++n)
        acc[4 + m][n] = __builtin_amdgcn_mfma_f32_16x16x32_bf16(
            afB[m], bfB[n], acc[4 + m][n], 0, 0, 0);
    ENDBAR();

    // ph4: read S5 (buf1.A m4-7 kk0); stage B(0,1,t2); Q0'
#pragma unroll
    for (int m = 0; m < 4; ++m)
      afB[m] = *(const bf16x8*)(aP[1] + (4 + m) * 2048 + offk0);
    stageB(0, 1, t2);
    WAIT_LGKM(4);
#pragma unroll
    for (int m = 0; m < 4; ++m)
#pragma unroll
      for (int n = 0; n < 4; ++n)
        acc[m][n] = __builtin_amdgcn_mfma_f32_16x16x32_bf16(afA[m], bfA[n],
                                                            acc[m][n], 0, 0, 0);
    ENDBAR();

    // ph5: read S6 (buf1.A m0-3 kk1 + buf1.B kk1); stage A(0,*,t2); Q1'
#pragma unroll
    for (int m = 0; m < 4; ++m)
      afA[m] = *(const bf16x8*)(aP[1] + m * 2048 + offk1);
#pragma unroll
    for (int n = 0; n < 4; ++n)
      bfB[n] = *(const bf16x8*)(bP[1] + n * 2048 + offk1);
    stageA(0, 0, t2);
    stageA(0, 1, t2);
    WAIT_LGKM(8);
#pragma unroll
    for (int m = 0; m < 4; ++m)
#pragma unroll
      for (int n = 0; n < 4; ++n)
        acc[4 + m][n] = __builtin_amdgcn_mfma_f32_16x16x32_bf16(
            afB[m], bfA[n], acc[4 + m][n], 0, 0, 0);
    ENDBAR();

    // ph6: read S7 (buf1.A m4-7 kk1); Q2'; END: vmcnt(0) [buf0' landed]
#pragma unroll
    for (int m = 0; m < 4; ++m)
      afB[m] = *(const bf16x8*)(aP[1] + (4 + m) * 2048 + offk1);
    WAIT_LGKM(4);
#pragma unroll
    for (int m = 0; m < 4; ++m)
#pragma unroll
      for (int n = 0; n < 4; ++n)
        acc[m][n] = __builtin_amdgcn_mfma_f32_16x16x32_bf16(afA[m], bfB[n],
                                                            acc[m][n], 0, 0, 0);
    ENDBAR_VM0();

    // ph7: read S0' (buf0 NEW tile); stage B(1,0,t3); Q3'
#pragma unroll
    for (int m = 0; m < 4; ++m)
      afA[m] = *(const bf16x8*)(aP[0] + m * 2048 + offk0);
#pragma unroll
    for (int n = 0; n < 4; ++n)
      bfA[n] = *(const bf16x8*)(bP[0] + n * 2048 + offk0);
    stageB(1, 0, t3);
    WAIT_LGKM(8);
#pragma unroll
    for (int m = 0; m < 4; ++m)
#pragma unroll
      for (int n = 0; n < 4; ++n)
        acc[4 + m][n] = __builtin_amdgcn_mfma_f32_16x16x32_bf16(
            afB[m], bfB[n], acc[4 + m][n], 0, 0, 0);
    ENDBAR();
  }

  // ---- epilogue: C/D layout col=lane&15, row=(lane>>4)*4+j ----
  // Nontemporal stores: C is write-once; don't evict L3-resident A/B panels.
  const int crow0 = brow + wm * 128 + q4 * 4;
  const int ccol0 = bcol + wn * 64 + l15;
#pragma unroll
  for (int n = 0; n < 4; ++n) {
    const float bv = bias[ccol0 + n * 16];
#pragma unroll
    for (int m = 0; m < 8; ++m) {
      const size_t rb = (size_t)(crow0 + m * 16) * N_DIM + (ccol0 + n * 16);
#pragma unroll
      for (int j = 0; j < 4; ++j)
        __builtin_nontemporal_store(acc[m][n][j] + bv,
                                    &C[rb + (size_t)j * N_DIM]);
    }
  }
}

extern "C" void kernel_launch(void* const* d_in, const int* in_sizes, int n_in,
                              void* d_out, int out_size, void* d_ws, size_t ws_size,
                              hipStream_t stream) {
  const float* x = (const float*)d_in[0];     // [8192, 4096]
  const float* w = (const float*)d_in[1];     // [11008, 4096]
  const float* bias = (const float*)d_in[2];  // [11008]
  float* out = (float*)d_out;                 // [8192, 11008]

  unsigned short* wq = (unsigned short*)d_ws;       // N*K bf16
  unsigned short* xb = wq + (size_t)N_DIM * K_DIM;  // M*K bf16

  prep_kernel<<<NQB + NCB, 256, 0, stream>>>(w, wq, x, (uint32_t*)xb);
  // 1376 = (8192/256) * (11008/256) = 8 XCD-chunks x 172 (ragged 5.375
  // rounds -- measured cheaper than every tail-split variant, R8-R10)
  gemm256_kernel<<<dim3(1376), 512, 0, stream>>>((const short*)xb,
                                                 (const short*)wq, bias, out);
}